// Round 6
// baseline (59.470 us; speedup 1.0000x reference)
//
#include <hip/hip_runtime.h>
#include <stdint.h>

#define D_DIM 2048
#define B_DIM 4096
#define BMT 128                       // output tile M = N
#define BKB 128                       // K step in BYTES (= 128 fp8 elements)
#define NKS (B_DIM / 128)             // 32 K-steps total
#define NTILE (D_DIM / BMT)           // 16
#define NPAIR ((NTILE * (NTILE + 1)) / 2)  // 136 upper-triangle tile pairs
// Non-uniform K-split: 104 pairs x 4 + 32 pairs x 3 = 512 blocks = exactly 2/CU
#define P4 104
#define GRAM_BLOCKS (P4 * 4 + (NPAIR - P4) * 3)   // 512 = 8 XCDs x 64
#define MWORDS (D_DIM / 64)           // 32 mask words per row
#define NT32 (D_DIM / 64)             // 32 row-blocks for mask part
#define MPAIR ((NT32 * (NT32 + 1)) / 2)  // 528 upper mask block pairs
#define TP_BLOCKS ((D_DIM / 64) * (B_DIM / 64))  // 2048 transpose blocks

typedef __attribute__((ext_vector_type(4))) float f32x4;
typedef __attribute__((ext_vector_type(4))) int   i32x4;
typedef __attribute__((ext_vector_type(8))) int   i32x8;

__device__ __forceinline__ void gload16(const void* g, void* lds) {
    __builtin_amdgcn_global_load_lds((__attribute__((address_space(1))) void*)g,
                                     (__attribute__((address_space(3))) void*)lds,
                                     16, 0, 0);
}

// Fused prep: transpose X -> fp8 XT (blocks [0, TP_BLOCKS)) and build the packed
// upper-triangle mask + edge count (blocks [TP_BLOCKS, TP_BLOCKS+MPAIR)).
// gsum/gcnt/ticket are zeroed by a hipMemsetAsync BEFORE this dispatch (no init race).
__global__ __launch_bounds__(256) void prep_kernel(
    const float* __restrict__ X, const float* __restrict__ ddi,
    unsigned char* __restrict__ XT8, unsigned long long* __restrict__ mask64,
    int* __restrict__ gcnt)
{
    __shared__ float tile[64][65];
    __shared__ int redi[4];
    const int tid = threadIdx.x;

    if (blockIdx.x < TP_BLOCKS) {
        // ---- transpose + f32->fp8(e4m3, RNE) ----
        const int i0 = (blockIdx.x & 31) * 64;   // D/64 = 32 column blocks of X
        const int k0 = (blockIdx.x >> 5) * 64;   // row block of X

        const int c4 = tid & 15;
        const int rr = tid >> 4;
        #pragma unroll
        for (int p = 0; p < 4; ++p) {
            const int kr = p * 16 + rr;
            const float4 v = *reinterpret_cast<const float4*>(
                &X[(size_t)(k0 + kr) * D_DIM + i0 + c4 * 4]);
            tile[kr][c4 * 4 + 0] = v.x;
            tile[kr][c4 * 4 + 1] = v.y;
            tile[kr][c4 * 4 + 2] = v.z;
            tile[kr][c4 * 4 + 3] = v.w;
        }
        __syncthreads();

        const int ir16 = tid >> 4;
        const int kq   = tid & 15;
        #pragma unroll
        for (int pi = 0; pi < 4; ++pi) {
            const int ir = pi * 16 + ir16;
            const int kc = kq * 4;
            int pk = __builtin_amdgcn_cvt_pk_fp8_f32(tile[kc + 0][ir], tile[kc + 1][ir], 0, false);
            pk     = __builtin_amdgcn_cvt_pk_fp8_f32(tile[kc + 2][ir], tile[kc + 3][ir], pk, true);
            *reinterpret_cast<int*>(XT8 + (size_t)(i0 + ir) * B_DIM + k0 + kc) = pk;
        }
    } else {
        // ---- mask: bit (i,j) = (i<j) && (ddi[i][j]>0 || ddi[j][i]>0), 64x64 block pairs bi<=bj ----
        const int mb = blockIdx.x - TP_BLOCKS;
        int bi = 0, rem = mb;
        while (rem >= NT32 - bi) { rem -= NT32 - bi; ++bi; }
        const int bj = bi + rem;
        const int r0 = bi * 64;
        const int c0 = bj * 64;

        const int c4 = tid & 15;
        const int rr = tid >> 4;
        #pragma unroll
        for (int p = 0; p < 4; ++p) {
            const int kr = p * 16 + rr;
            const float4 v = *reinterpret_cast<const float4*>(
                &ddi[(size_t)(c0 + kr) * D_DIM + r0 + c4 * 4]);
            tile[kr][c4 * 4 + 0] = v.x;
            tile[kr][c4 * 4 + 1] = v.y;
            tile[kr][c4 * 4 + 2] = v.z;
            tile[kr][c4 * 4 + 3] = v.w;
        }
        __syncthreads();

        const int lane = tid & 63;
        const int w    = tid >> 6;
        int cnt = 0;
        #pragma unroll
        for (int rr2 = 0; rr2 < 16; ++rr2) {
            const int li = w * 16 + rr2;
            const int gi = r0 + li;
            const int gj = c0 + lane;
            const float a  = ddi[(size_t)gi * D_DIM + c0 + lane];  // coalesced row read
            const float at = tile[lane][li];                       // ddi[gj][gi]
            const bool bit = (gi < gj) && (a > 0.f || at > 0.f);
            const unsigned long long word = __ballot(bit);
            if (lane == 0) mask64[(size_t)gi * MWORDS + bj] = word;
            cnt += bit ? 1 : 0;
        }
        #pragma unroll
        for (int off = 32; off > 0; off >>= 1) cnt += __shfl_down(cnt, off, 64);
        if (lane == 0) redi[w] = cnt;
        __syncthreads();
        if (tid == 0) atomicAdd(gcnt, redi[0] + redi[1] + redi[2] + redi[3]);
    }
}

// Read one 32-byte (K=128-slice) MX-MFMA fragment from the XOR-swizzled LDS tile.
// Lane's 32 B = granules {2g, 2g+1} of row; swizzle maps them to slots {s, s^1}
// (adjacency preserved since XOR acts identically on both). 2x ds_read_b128, 2-way banks.
__device__ __forceinline__ i32x8 frag_read(const unsigned char* ls, int row, int g) {
    const int s = (2 * g) ^ (row & 7);
    const i32x4 lo = *reinterpret_cast<const i32x4*>(ls + row * BKB + s * 16);
    const i32x4 hi = *reinterpret_cast<const i32x4*>(ls + row * BKB + (s ^ 1) * 16);
    i32x8 r;
    r[0] = lo[0]; r[1] = lo[1]; r[2] = lo[2]; r[3] = lo[3];
    r[4] = hi[0]; r[5] = hi[1]; r[6] = hi[2]; r[7] = hi[3];
    return r;
}

// Gram = XT8_panel_i · XT8_panel_j^T, MX-scaled fp8 e4m3 (unit scales), K=128/MFMA.
// 128x128 tile, 4 waves (2x2 of 64x64), DOUBLE-buffered LDS (64 KiB -> 2 blocks/CU),
// T3-minimum 2-phase: stage(t+1) issued BEFORE compute(t); the end-of-iter barrier's
// vmcnt(0) drain lands after the full ds_read+MFMA phase -> load latency hidden.
// Grid 512 = 2/CU exactly (104 pairs x 4 splits + 32 x 3), XCD-bijective (512 = 8x64).
// Self-finalizing: last block (device-scope ticket) computes out = gsum/(B*max(cnt,1)).
__global__ __launch_bounds__(256) void gram_masked_kernel(
    const unsigned char* __restrict__ XT8,
    const unsigned long long* __restrict__ mask64,
    float* __restrict__ gsum, int* __restrict__ gcnt, int* __restrict__ ticket,
    float* __restrict__ out)
{
    __shared__ __align__(16) unsigned char lsA[2][BMT * BKB];   // 2 x 16 KiB
    __shared__ __align__(16) unsigned char lsB[2][BMT * BKB];   // 2 x 16 KiB
    __shared__ float redf[4];
    __shared__ int lastFlag;

    const int tid  = threadIdx.x;
    const int lane = tid & 63;
    const int w    = tid >> 6;        // wave 0..3
    const int wr   = w >> 1, wc = w & 1;
    const int m16  = lane & 15;
    const int g    = lane >> 4;       // k-group 0..3 (32 B each of the 128 B row)

    // XCD-chunked bijective ordering: XCD (bid%8) covers logical chunk of 64.
    const int bid = blockIdx.x;
    const int logical = (bid & 7) * (GRAM_BLOCKS / 8) + (bid >> 3);

    // Non-uniform K-split decode: first 104 pairs -> 4 splits, rest -> 3.
    int pair, s, ns;
    if (logical < P4 * 4) { pair = logical >> 2; s = logical & 3; ns = 4; }
    else { const int t = logical - P4 * 4; pair = P4 + t / 3; s = t % 3; ns = 3; }

    int ti = 0, rem = pair;
    while (rem >= NTILE - ti) { rem -= NTILE - ti; ++ti; }
    const int tj = ti + rem;
    const int i0 = ti * BMT, j0 = tj * BMT;

    const int ks0 = (NKS * s) / ns;           // K-step range [ks0, ks1): 8 or 10-11 steps
    const int ks1 = (NKS * (s + 1)) / ns;
    const int nkt = ks1 - ks0;
    const int kbase = ks0 * BKB;              // byte offset into the 4096-byte K row

    f32x4 acc[4][4];
    #pragma unroll
    for (int a = 0; a < 4; ++a)
        #pragma unroll
        for (int b = 0; b < 4; ++b)
            acc[a][b] = (f32x4){0.f, 0.f, 0.f, 0.f};

    // Staging: chunk = p*256 + tid; 16B granules, row = chunk/8 (8 granules per 128 B row).
    // Linear LDS dest + inverse-swizzled global source: slot (row,c) gets granule (row, c^(row&7)).
    size_t gaoff[4], gboff[4];
    #pragma unroll
    for (int p = 0; p < 4; ++p) {
        const int chunk = p * 256 + tid;
        const int row = chunk >> 3;
        const int sc = (chunk & 7) ^ (row & 7);
        gaoff[p] = (size_t)(i0 + row) * B_DIM + kbase + sc * 16;
        gboff[p] = (size_t)(j0 + row) * B_DIM + kbase + sc * 16;
    }

    auto stage = [&](int buf, int kt) {
        char* bA = (char*)lsA[buf] + (size_t)w * 1024;   // wave-uniform segment base
        char* bB = (char*)lsB[buf] + (size_t)w * 1024;
        const int koff = kt * BKB;
        #pragma unroll
        for (int p = 0; p < 4; ++p) {
            gload16(XT8 + gaoff[p] + koff, bA + p * 4096);
            gload16(XT8 + gboff[p] + koff, bB + p * 4096);
        }
    };

    stage(0, 0);
    __syncthreads();                  // buf0 ready (vmcnt(0) drained by compiler)
    int cur = 0;
    for (int kt = 0; kt < nkt; ++kt) {
        if (kt + 1 < nkt) stage(cur ^ 1, kt + 1);   // issue next-tile loads FIRST

        i32x8 aF[4], bF[4];
        #pragma unroll
        for (int f = 0; f < 4; ++f) {
            aF[f] = frag_read(lsA[cur], wr * 64 + f * 16 + m16, g);
            bF[f] = frag_read(lsB[cur], wc * 64 + f * 16 + m16, g);
        }
        #pragma unroll
        for (int fi = 0; fi < 4; ++fi)
            #pragma unroll
            for (int fj = 0; fj < 4; ++fj)
                acc[fi][fj] = __builtin_amdgcn_mfma_scale_f32_16x16x128_f8f6f4(
                    aF[fi], bF[fj], acc[fi][fj],
                    0 /*A fmt: fp8 e4m3*/, 0 /*B fmt: fp8 e4m3*/,
                    0, 0x7F7F7F7F /*A scales = 1.0*/,
                    0, 0x7F7F7F7F /*B scales = 1.0*/);

        if (kt + 1 < nkt) {
            __syncthreads();          // drains prefetch vmcnt + guards buffer reuse
            cur ^= 1;
        }
    }

    // Fused epilogue: masked sum from packed bits (mask encodes i<j already).
    // C/D layout: col = lane&15, row = (lane>>4)*4 + reg  [m89/m91; shape-determined]
    // Guard: words entirely below the diagonal are unwritten (poison) — skip them.
    float lsum = 0.f;
    const int jb = (j0 + wc * 64) >> 6;
    #pragma unroll
    for (int fi = 0; fi < 4; ++fi) {
        #pragma unroll
        for (int r = 0; r < 4; ++r) {
            const int i = i0 + wr * 64 + fi * 16 + g * 4 + r;
            unsigned long long wword = 0ull;
            if (jb * 64 + 63 > i) wword = mask64[(size_t)i * MWORDS + jb];
            #pragma unroll
            for (int fj = 0; fj < 4; ++fj) {
                if ((wword >> (fj * 16 + m16)) & 1ull) lsum += acc[fi][fj][r];
            }
        }
    }
    #pragma unroll
    for (int off = 32; off > 0; off >>= 1) lsum += __shfl_down(lsum, off, 64);
    if (lane == 0) redf[w] = lsum;
    __syncthreads();

    // Ticketed finalize: the last block to arrive computes the output.
    if (tid == 0) {
        atomicAdd(gsum, redf[0] + redf[1] + redf[2] + redf[3]);
        __threadfence();                         // order gsum add before ticket
        const int old = atomicAdd(ticket, 1);    // device-scope
        lastFlag = (old == GRAM_BLOCKS - 1);
    }
    __syncthreads();
    if (lastFlag && tid == 0) {
        __threadfence();
        const float s2  = atomicAdd(gsum, 0.0f); // coherent read
        const int   cnt = atomicAdd(gcnt, 0);
        out[0] = s2 / ((float)B_DIM * fmaxf((float)cnt, 1.0f));
    }
}

extern "C" void kernel_launch(void* const* d_in, const int* in_sizes, int n_in,
                              void* d_out, int out_size, void* d_ws, size_t ws_size,
                              hipStream_t stream) {
    const float* X   = (const float*)d_in[0];   // drug_probs (B_DIM x D_DIM)
    const float* ddi = (const float*)d_in[1];   // ddi_matrix (D_DIM x D_DIM)
    float* out = (float*)d_out;

    const size_t XT_BYTES   = (size_t)D_DIM * B_DIM;                                // 8 MiB fp8
    const size_t MASK_BYTES = (size_t)D_DIM * MWORDS * sizeof(unsigned long long);  // 512 KiB
    if (ws_size < XT_BYTES + MASK_BYTES + 64) return;

    unsigned char* XT8 = (unsigned char*)d_ws;
    unsigned long long* mask64 = (unsigned long long*)((char*)d_ws + XT_BYTES);
    char* ctrl = (char*)d_ws + XT_BYTES + MASK_BYTES;
    float* gsum   = (float*)(ctrl + 0);
    int*   gcnt   = (int*)(ctrl + 4);
    int*   ticket = (int*)(ctrl + 8);

    hipMemsetAsync(ctrl, 0, 16, stream);        // zero gsum/gcnt/ticket (capturable)
    prep_kernel<<<TP_BLOCKS + MPAIR, 256, 0, stream>>>(X, ddi, XT8, mask64, gcnt);
    gram_masked_kernel<<<GRAM_BLOCKS, 256, 0, stream>>>(XT8, mask64, gsum, gcnt, ticket, out);
}

// Round 7
// 50.579 us; speedup vs baseline: 1.1758x; 1.1758x over previous
//
#include <hip/hip_runtime.h>
#include <stdint.h>

#define D_DIM 2048
#define B_DIM 4096
#define BMT 128                       // output tile M = N
#define BKB 128                       // K step in BYTES (= 128 fp8 elements)
#define NKS (B_DIM / 128)             // 32 K-steps total
#define NTILE (D_DIM / BMT)           // 16
#define NPAIR ((NTILE * (NTILE + 1)) / 2)  // 136 upper-triangle tile pairs
// Non-uniform K-split: 104 pairs x 4 + 32 pairs x 3 = 512 blocks = exactly 2/CU
#define P4 104
#define GRAM_BLOCKS (P4 * 4 + (NPAIR - P4) * 3)   // 512 = 8 XCDs x 64
#define MWORDS (D_DIM / 64)           // 32 mask words per row
#define NT32 (D_DIM / 64)             // 32 row-blocks for mask part
#define MPAIR ((NT32 * (NT32 + 1)) / 2)  // 528 upper mask block pairs
#define TP_BLOCKS ((D_DIM / 64) * (B_DIM / 64))  // 2048 transpose blocks

typedef __attribute__((ext_vector_type(4))) float f32x4;
typedef __attribute__((ext_vector_type(4))) int   i32x4;
typedef __attribute__((ext_vector_type(8))) int   i32x8;

__device__ __forceinline__ void gload16(const void* g, void* lds) {
    __builtin_amdgcn_global_load_lds((__attribute__((address_space(1))) void*)g,
                                     (__attribute__((address_space(3))) void*)lds,
                                     16, 0, 0);
}

// Fused prep: transpose X -> fp8 XT (blocks [0, TP_BLOCKS)) and build the packed
// upper-triangle mask + per-block edge counts (blocks [TP_BLOCKS, TP_BLOCKS+MPAIR)).
// Block 0 zero-inits gsum/ticket (no other prep block touches them; kernel-boundary
// ordering makes the zeros visible to the gram dispatch). NO memset node — a 16-byte
// hipMemsetAsync cost 41 us as a graph node (r6 counter evidence, WRITE_SIZE=0.031KB).
__global__ __launch_bounds__(256) void prep_kernel(
    const float* __restrict__ X, const float* __restrict__ ddi,
    unsigned char* __restrict__ XT8, unsigned long long* __restrict__ mask64,
    int* __restrict__ partials, float* __restrict__ gsum, int* __restrict__ ticket)
{
    __shared__ float tile[64][65];
    __shared__ int redi[4];
    const int tid = threadIdx.x;

    if (blockIdx.x < TP_BLOCKS) {
        // ---- transpose + f32->fp8(e4m3, RNE) ----
        if (blockIdx.x == 0 && tid == 0) { *gsum = 0.f; *ticket = 0; }
        const int i0 = (blockIdx.x & 31) * 64;   // D/64 = 32 column blocks of X
        const int k0 = (blockIdx.x >> 5) * 64;   // row block of X

        const int c4 = tid & 15;
        const int rr = tid >> 4;
        #pragma unroll
        for (int p = 0; p < 4; ++p) {
            const int kr = p * 16 + rr;
            const float4 v = *reinterpret_cast<const float4*>(
                &X[(size_t)(k0 + kr) * D_DIM + i0 + c4 * 4]);
            tile[kr][c4 * 4 + 0] = v.x;
            tile[kr][c4 * 4 + 1] = v.y;
            tile[kr][c4 * 4 + 2] = v.z;
            tile[kr][c4 * 4 + 3] = v.w;
        }
        __syncthreads();

        const int ir16 = tid >> 4;
        const int kq   = tid & 15;
        #pragma unroll
        for (int pi = 0; pi < 4; ++pi) {
            const int ir = pi * 16 + ir16;
            const int kc = kq * 4;
            int pk = __builtin_amdgcn_cvt_pk_fp8_f32(tile[kc + 0][ir], tile[kc + 1][ir], 0, false);
            pk     = __builtin_amdgcn_cvt_pk_fp8_f32(tile[kc + 2][ir], tile[kc + 3][ir], pk, true);
            *reinterpret_cast<int*>(XT8 + (size_t)(i0 + ir) * B_DIM + k0 + kc) = pk;
        }
    } else {
        // ---- mask: bit (i,j) = (i<j) && (ddi[i][j]>0 || ddi[j][i]>0), 64x64 block pairs bi<=bj ----
        const int mb = blockIdx.x - TP_BLOCKS;
        int bi = 0, rem = mb;
        while (rem >= NT32 - bi) { rem -= NT32 - bi; ++bi; }
        const int bj = bi + rem;
        const int r0 = bi * 64;
        const int c0 = bj * 64;

        const int c4 = tid & 15;
        const int rr = tid >> 4;
        #pragma unroll
        for (int p = 0; p < 4; ++p) {
            const int kr = p * 16 + rr;
            const float4 v = *reinterpret_cast<const float4*>(
                &ddi[(size_t)(c0 + kr) * D_DIM + r0 + c4 * 4]);
            tile[kr][c4 * 4 + 0] = v.x;
            tile[kr][c4 * 4 + 1] = v.y;
            tile[kr][c4 * 4 + 2] = v.z;
            tile[kr][c4 * 4 + 3] = v.w;
        }
        __syncthreads();

        const int lane = tid & 63;
        const int w    = tid >> 6;
        int cnt = 0;
        #pragma unroll
        for (int rr2 = 0; rr2 < 16; ++rr2) {
            const int li = w * 16 + rr2;
            const int gi = r0 + li;
            const int gj = c0 + lane;
            const float a  = ddi[(size_t)gi * D_DIM + c0 + lane];  // coalesced row read
            const float at = tile[lane][li];                       // ddi[gj][gi]
            const bool bit = (gi < gj) && (a > 0.f || at > 0.f);
            const unsigned long long word = __ballot(bit);
            if (lane == 0) mask64[(size_t)gi * MWORDS + bj] = word;
            cnt += bit ? 1 : 0;
        }
        #pragma unroll
        for (int off = 32; off > 0; off >>= 1) cnt += __shfl_down(cnt, off, 64);
        if (lane == 0) redi[w] = cnt;
        __syncthreads();
        if (tid == 0) partials[mb] = redi[0] + redi[1] + redi[2] + redi[3];  // race-free, rewritten every call
    }
}

// Read one 32-byte (K=128-slice) MX-MFMA fragment from the XOR-swizzled LDS tile.
// Lane's 32 B = granules {2g, 2g+1} of row; swizzle maps them to slots {s, s^1}
// (adjacency preserved since XOR acts identically on both). 2x ds_read_b128, 2-way banks.
__device__ __forceinline__ i32x8 frag_read(const unsigned char* ls, int row, int g) {
    const int s = (2 * g) ^ (row & 7);
    const i32x4 lo = *reinterpret_cast<const i32x4*>(ls + row * BKB + s * 16);
    const i32x4 hi = *reinterpret_cast<const i32x4*>(ls + row * BKB + (s ^ 1) * 16);
    i32x8 r;
    r[0] = lo[0]; r[1] = lo[1]; r[2] = lo[2]; r[3] = lo[3];
    r[4] = hi[0]; r[5] = hi[1]; r[6] = hi[2]; r[7] = hi[3];
    return r;
}

// Gram = XT8_panel_i · XT8_panel_j^T, MX-scaled fp8 e4m3 (unit scales), K=128/MFMA.
// 128x128 tile, 4 waves (2x2 of 64x64), DOUBLE-buffered LDS (64 KiB -> 2 blocks/CU),
// T3-minimum 2-phase: stage(t+1) issued BEFORE compute(t). Grid 512 = 2/CU exactly,
// XCD-bijective (512 = 8x64). Self-finalizing via device-scope ticket: last block
// sums mask partials + computes out = gsum/(B*max(cnt,1)).
__global__ __launch_bounds__(256) void gram_masked_kernel(
    const unsigned char* __restrict__ XT8,
    const unsigned long long* __restrict__ mask64,
    const int* __restrict__ partials,
    float* __restrict__ gsum, int* __restrict__ ticket,
    float* __restrict__ out)
{
    __shared__ __align__(16) unsigned char lsA[2][BMT * BKB];   // 2 x 16 KiB
    __shared__ __align__(16) unsigned char lsB[2][BMT * BKB];   // 2 x 16 KiB
    __shared__ float redf[4];
    __shared__ int redi[4];
    __shared__ int lastFlag;

    const int tid  = threadIdx.x;
    const int lane = tid & 63;
    const int w    = tid >> 6;        // wave 0..3
    const int wr   = w >> 1, wc = w & 1;
    const int m16  = lane & 15;
    const int g    = lane >> 4;       // k-group 0..3 (32 B each of the 128 B row)

    // XCD-chunked bijective ordering: XCD (bid%8) covers logical chunk of 64.
    const int bid = blockIdx.x;
    const int logical = (bid & 7) * (GRAM_BLOCKS / 8) + (bid >> 3);

    // Non-uniform K-split decode: first 104 pairs -> 4 splits, rest -> 3.
    int pair, s, ns;
    if (logical < P4 * 4) { pair = logical >> 2; s = logical & 3; ns = 4; }
    else { const int t = logical - P4 * 4; pair = P4 + t / 3; s = t % 3; ns = 3; }

    int ti = 0, rem = pair;
    while (rem >= NTILE - ti) { rem -= NTILE - ti; ++ti; }
    const int tj = ti + rem;
    const int i0 = ti * BMT, j0 = tj * BMT;

    const int ks0 = (NKS * s) / ns;           // K-step range [ks0, ks1): 8 or 10-11 steps
    const int ks1 = (NKS * (s + 1)) / ns;
    const int nkt = ks1 - ks0;
    const int kbase = ks0 * BKB;              // byte offset into the 4096-byte K row

    f32x4 acc[4][4];
    #pragma unroll
    for (int a = 0; a < 4; ++a)
        #pragma unroll
        for (int b = 0; b < 4; ++b)
            acc[a][b] = (f32x4){0.f, 0.f, 0.f, 0.f};

    // Staging: chunk = p*256 + tid; 16B granules, row = chunk/8 (8 granules per 128 B row).
    // Linear LDS dest + inverse-swizzled global source: slot (row,c) gets granule (row, c^(row&7)).
    size_t gaoff[4], gboff[4];
    #pragma unroll
    for (int p = 0; p < 4; ++p) {
        const int chunk = p * 256 + tid;
        const int row = chunk >> 3;
        const int sc = (chunk & 7) ^ (row & 7);
        gaoff[p] = (size_t)(i0 + row) * B_DIM + kbase + sc * 16;
        gboff[p] = (size_t)(j0 + row) * B_DIM + kbase + sc * 16;
    }

    auto stage = [&](int buf, int kt) {
        char* bA = (char*)lsA[buf] + (size_t)w * 1024;   // wave-uniform segment base
        char* bB = (char*)lsB[buf] + (size_t)w * 1024;
        const int koff = kt * BKB;
        #pragma unroll
        for (int p = 0; p < 4; ++p) {
            gload16(XT8 + gaoff[p] + koff, bA + p * 4096);
            gload16(XT8 + gboff[p] + koff, bB + p * 4096);
        }
    };

    stage(0, 0);
    __syncthreads();                  // buf0 ready (vmcnt(0) drained by compiler)
    int cur = 0;
    for (int kt = 0; kt < nkt; ++kt) {
        if (kt + 1 < nkt) stage(cur ^ 1, kt + 1);   // issue next-tile loads FIRST

        i32x8 aF[4], bF[4];
        #pragma unroll
        for (int f = 0; f < 4; ++f) {
            aF[f] = frag_read(lsA[cur], wr * 64 + f * 16 + m16, g);
            bF[f] = frag_read(lsB[cur], wc * 64 + f * 16 + m16, g);
        }
        #pragma unroll
        for (int fi = 0; fi < 4; ++fi)
            #pragma unroll
            for (int fj = 0; fj < 4; ++fj)
                acc[fi][fj] = __builtin_amdgcn_mfma_scale_f32_16x16x128_f8f6f4(
                    aF[fi], bF[fj], acc[fi][fj],
                    0 /*A fmt: fp8 e4m3*/, 0 /*B fmt: fp8 e4m3*/,
                    0, 0x7F7F7F7F /*A scales = 1.0*/,
                    0, 0x7F7F7F7F /*B scales = 1.0*/);

        if (kt + 1 < nkt) {
            __syncthreads();          // drains prefetch vmcnt + guards buffer reuse
            cur ^= 1;
        }
    }

    // Fused epilogue: masked sum from packed bits (mask encodes i<j already).
    // C/D layout: col = lane&15, row = (lane>>4)*4 + reg  [m89/m91; shape-determined]
    // Guard: words entirely below the diagonal are unwritten (poison) — skip them.
    float lsum = 0.f;
    const int jb = (j0 + wc * 64) >> 6;
    #pragma unroll
    for (int fi = 0; fi < 4; ++fi) {
        #pragma unroll
        for (int r = 0; r < 4; ++r) {
            const int i = i0 + wr * 64 + fi * 16 + g * 4 + r;
            unsigned long long wword = 0ull;
            if (jb * 64 + 63 > i) wword = mask64[(size_t)i * MWORDS + jb];
            #pragma unroll
            for (int fj = 0; fj < 4; ++fj) {
                if ((wword >> (fj * 16 + m16)) & 1ull) lsum += acc[fi][fj][r];
            }
        }
    }
    #pragma unroll
    for (int off = 32; off > 0; off >>= 1) lsum += __shfl_down(lsum, off, 64);
    if (lane == 0) redf[w] = lsum;
    __syncthreads();

    // Ticketed finalize: the last block to arrive sums partials + computes the output.
    if (tid == 0) {
        atomicAdd(gsum, redf[0] + redf[1] + redf[2] + redf[3]);
        __threadfence();                         // order gsum add before ticket
        const int old = atomicAdd(ticket, 1);    // device-scope
        lastFlag = (old == GRAM_BLOCKS - 1);
    }
    __syncthreads();
    if (lastFlag) {                               // block-uniform
        int sc = 0;
        for (int i = tid; i < MPAIR; i += 256) sc += partials[i];
        #pragma unroll
        for (int off = 32; off > 0; off >>= 1) sc += __shfl_down(sc, off, 64);
        if (lane == 0) redi[w] = sc;
        __syncthreads();
        if (tid == 0) {
            __threadfence();
            const float s2  = atomicAdd(gsum, 0.0f); // coherent read of all blocks' adds
            const int   cnt = redi[0] + redi[1] + redi[2] + redi[3];
            out[0] = s2 / ((float)B_DIM * fmaxf((float)cnt, 1.0f));
        }
    }
}

extern "C" void kernel_launch(void* const* d_in, const int* in_sizes, int n_in,
                              void* d_out, int out_size, void* d_ws, size_t ws_size,
                              hipStream_t stream) {
    const float* X   = (const float*)d_in[0];   // drug_probs (B_DIM x D_DIM)
    const float* ddi = (const float*)d_in[1];   // ddi_matrix (D_DIM x D_DIM)
    float* out = (float*)d_out;

    const size_t XT_BYTES   = (size_t)D_DIM * B_DIM;                                // 8 MiB fp8
    const size_t MASK_BYTES = (size_t)D_DIM * MWORDS * sizeof(unsigned long long);  // 512 KiB
    const size_t PART_BYTES = (size_t)MPAIR * sizeof(int);
    if (ws_size < XT_BYTES + MASK_BYTES + PART_BYTES + 64) return;

    unsigned char* XT8 = (unsigned char*)d_ws;
    unsigned long long* mask64 = (unsigned long long*)((char*)d_ws + XT_BYTES);
    int*   partials = (int*)((char*)d_ws + XT_BYTES + MASK_BYTES);
    char*  ctrl     = (char*)d_ws + XT_BYTES + MASK_BYTES + PART_BYTES;
    float* gsum     = (float*)(ctrl + 0);
    int*   ticket   = (int*)(ctrl + 4);

    prep_kernel<<<TP_BLOCKS + MPAIR, 256, 0, stream>>>(X, ddi, XT8, mask64, partials, gsum, ticket);
    gram_masked_kernel<<<GRAM_BLOCKS, 256, 0, stream>>>(XT8, mask64, partials, gsum, ticket, out);
}